// Round 2
// baseline (4559.996 us; speedup 1.0000x reference)
//
#include <hip/hip_runtime.h>

#define NN 100000
#define TT 64
#define EE 1000000
#define LOG2E 1.44269504088896340736f

typedef __attribute__((ext_vector_type(8))) short bf16x8;
typedef __attribute__((ext_vector_type(4))) float f32x4;
typedef unsigned int u32;
typedef unsigned short u16;

__device__ __forceinline__ float bflo(u32 u) { return __builtin_bit_cast(float, u << 16); }
__device__ __forceinline__ float bfhi(u32 u) { return __builtin_bit_cast(float, u & 0xffff0000u); }
__device__ __forceinline__ u16 f2bf(float f) {
    u32 u = __builtin_bit_cast(u32, f);
    return (u16)((u + 0x7fffu + ((u >> 16) & 1u)) >> 16);
}
__device__ __forceinline__ float fast_rcp(float x) { return __builtin_amdgcn_rcpf(x); }
__device__ __forceinline__ float sigf(float v) { return fast_rcp(1.f + exp2f(-LOG2E * v)); }
__device__ __forceinline__ float tanhf_fast(float v) {
    return fmaf(2.f, fast_rcp(1.f + exp2f(-2.f * LOG2E * v)), -1.f);
}

// ---------------------------------------------------------------------------
// LSTM: 16 nodes per wave, MFMA 16x16x32 bf16 for h @ w_hh.T (K=64 -> 2 frags).
// Inputs are float32; w_hh converted to bf16 fragments once per block; h kept
// bf16 in per-wave LDS (same-wave DS is FIFO -> no per-step barrier).
// C/D: col=lane&15 (gate), row=(lane>>4)*4+reg (node). A: m=lane&15, k=8*(lane>>4)+j.
// ---------------------------------------------------------------------------
__global__ __launch_bounds__(256, 2) void lstm_kernel(
    const float2* __restrict__ x2,   // [NN*TT] (x[n][t][0], x[n][t][1])
    const float* __restrict__ w_ih,  // [256*2]
    const float* __restrict__ w_hh,  // [256*64]
    const float* __restrict__ b_ih,  // [256]
    const float* __restrict__ b_hh,  // [256]
    u16* __restrict__ h_out)         // [NN*64] bf16 (internal format)
{
    __shared__ __align__(16) u16 wfrag[32 * 64 * 8];   // 32 KB: B-fragments (bf16)
    __shared__ __align__(16) u16 h_buf[4][16][72];     // per-wave, pad 72 vs banks

    const int tid = threadIdx.x;
    const int wv = tid >> 6, lane = tid & 63;
    const int q = lane >> 4, cl = lane & 15;
    const int node_base = (blockIdx.x * 4 + wv) * 16;

    // stage B = w_hh^T fragments: frag f=(t,kh); value (lane,j) = w_hh[t*16+cl][kh*32+q*8+j]
    for (int f = wv; f < 32; f += 4) {
        int t = f >> 1, kh = f & 1;
        int n = t * 16 + cl;
        int k = kh * 32 + q * 8;
        const float* src = w_hh + n * 64 + k;
        u16* dstp = wfrag + (f * 64 + lane) * 8;
#pragma unroll
        for (int j = 0; j < 8; ++j) dstp[j] = f2bf(src[j]);
    }

    // per-lane x-projection coefficients for this lane's 16 gate columns (f32)
    float wih0[16], wih1[16], bias[16];
#pragma unroll
    for (int t = 0; t < 16; ++t) {
        int g = t * 16 + cl;
        wih0[t] = w_ih[g * 2 + 0];
        wih1[t] = w_ih[g * 2 + 1];
        bias[t] = b_ih[g] + b_hh[g];
    }

    u16* hb = &h_buf[wv][0][0];
    float cst[16];
#pragma unroll
    for (int i = 0; i < 16; ++i) cst[i] = 0.f;

    __syncthreads();  // wfrag ready (cross-wave)

    for (int step = 0; step < TT; ++step) {
        // x part for this lane's C rows (nodes q*4+r)
        float xf0[4], xf1[4];
#pragma unroll
        for (int r = 0; r < 4; ++r) {
            int nd = node_base + q * 4 + r;
            nd = nd < NN ? nd : NN - 1;
            float2 xv = x2[(size_t)nd * TT + step];
            xf0[r] = xv.x;
            xf1[r] = xv.y;
        }
        f32x4 acc[16];
#pragma unroll
        for (int t = 0; t < 16; ++t) {
#pragma unroll
            for (int r = 0; r < 4; ++r)
                acc[t][r] = fmaf(wih0[t], xf0[r], fmaf(wih1[t], xf1[r], bias[t]));
        }
        if (step > 0) {
            bf16x8 a0 = *(const bf16x8*)(hb + cl * 72 + q * 8);
            bf16x8 a1 = *(const bf16x8*)(hb + cl * 72 + 32 + q * 8);
#pragma unroll
            for (int t = 0; t < 16; ++t) {
                bf16x8 b0 = *(const bf16x8*)(wfrag + ((t * 2 + 0) * 64 + lane) * 8);
                bf16x8 b1 = *(const bf16x8*)(wfrag + ((t * 2 + 1) * 64 + lane) * 8);
                acc[t] = __builtin_amdgcn_mfma_f32_16x16x32_bf16(a0, b0, acc[t], 0, 0, 0);
                acc[t] = __builtin_amdgcn_mfma_f32_16x16x32_bf16(a1, b1, acc[t], 0, 0, 0);
            }
        }
        // elementwise: unit j = tt*16+cl, node = q*4+r  (gate tiles: i|f|g|o x4 each)
#pragma unroll
        for (int r = 0; r < 4; ++r) {
#pragma unroll
            for (int tt = 0; tt < 4; ++tt) {
                float ig = sigf(acc[tt][r]);
                float fg = sigf(acc[tt + 4][r]);
                float gg = tanhf_fast(acc[tt + 8][r]);
                float og = sigf(acc[tt + 12][r]);
                float cc = fmaf(fg, cst[r * 4 + tt], ig * gg);
                cst[r * 4 + tt] = cc;
                float hh = og * tanhf_fast(cc);
                hb[(q * 4 + r) * 72 + tt * 16 + cl] = f2bf(hh);
            }
        }
    }
    // write h to global (coalesced u32 pairs)
#pragma unroll
    for (int i = 0; i < 8; ++i) {
        int id = i * 64 + lane;
        int row = id >> 5, col2 = (id & 31) * 2;
        int nd = node_base + row;
        if (nd < NN) {
            u32 u = *(const u32*)(hb + row * 72 + col2);
            *((u32*)(h_out + (size_t)nd * 64 + col2)) = u;
        }
    }
}

// ---------------------------------------------------------------------------
// xh = h @ gat_w.T packed per-channel as (head0,head1) bf16 pair; attention dots
// one wave per node; f32 accumulation before bf16 rounding.
// ---------------------------------------------------------------------------
__global__ __launch_bounds__(256) void xh_kernel(
    const u16* __restrict__ h,        // [NN*64] bf16 (internal)
    const float* __restrict__ gat_w,  // [128*64] f32
    const float* __restrict__ att_src,// [2*64] f32
    const float* __restrict__ att_dst,// [2*64] f32
    u32* __restrict__ xh,             // [NN*64] packed bf16 pairs
    float2* __restrict__ asrc,
    float2* __restrict__ adst)
{
    __shared__ float hsh[4][64];
    int wv = threadIdx.x >> 6, lane = threadIdx.x & 63;
    int node = blockIdx.x * 4 + wv;
    hsh[wv][lane] = bflo((u32)h[(size_t)node * 64 + lane] << 0) , hsh[wv][lane] = __builtin_bit_cast(float, ((u32)h[(size_t)node * 64 + lane]) << 16);
    __syncthreads();
    const float4* w0p = (const float4*)(gat_w + (size_t)lane * 64);
    const float4* w1p = (const float4*)(gat_w + (size_t)(64 + lane) * 64);
    float a0 = 0.f, a1 = 0.f;
#pragma unroll
    for (int k = 0; k < 64; k += 4) {
        float4 w0 = w0p[k >> 2], w1 = w1p[k >> 2];
        float h0 = hsh[wv][k], h1 = hsh[wv][k + 1];
        float h2 = hsh[wv][k + 2], h3 = hsh[wv][k + 3];
        a0 = fmaf(h0, w0.x, a0); a0 = fmaf(h1, w0.y, a0);
        a0 = fmaf(h2, w0.z, a0); a0 = fmaf(h3, w0.w, a0);
        a1 = fmaf(h0, w1.x, a1); a1 = fmaf(h1, w1.y, a1);
        a1 = fmaf(h2, w1.z, a1); a1 = fmaf(h3, w1.w, a1);
    }
    xh[(size_t)node * 64 + lane] = (u32)f2bf(a0) | ((u32)f2bf(a1) << 16);
    float ps0 = a0 * att_src[lane];
    float ps1 = a1 * att_src[64 + lane];
    float pd0 = a0 * att_dst[lane];
    float pd1 = a1 * att_dst[64 + lane];
#pragma unroll
    for (int off = 32; off > 0; off >>= 1) {
        ps0 += __shfl_xor(ps0, off);
        ps1 += __shfl_xor(ps1, off);
        pd0 += __shfl_xor(pd0, off);
        pd1 += __shfl_xor(pd1, off);
    }
    if (lane == 0) {
        asrc[node] = make_float2(ps0, ps1);
        adst[node] = make_float2(pd0, pd1);
    }
}

// ------------------------- CSR build -------------------------
__global__ void hist_kernel(const int* __restrict__ ei, u32* __restrict__ deg) {
    int e = blockIdx.x * 256 + threadIdx.x;
    if (e < EE) atomicAdd(&deg[ei[EE + e]], 1u);
}

__global__ void scan1_kernel(u32* rp, u32* bsum) {
    __shared__ u32 tmp[256];
    int i = blockIdx.x * 256 + threadIdx.x;
    u32 v = (i < NN) ? rp[i] : 0u;
    tmp[threadIdx.x] = v;
    __syncthreads();
    for (int off = 1; off < 256; off <<= 1) {
        u32 t = (threadIdx.x >= (u32)off) ? tmp[threadIdx.x - off] : 0u;
        __syncthreads();
        tmp[threadIdx.x] += t;
        __syncthreads();
    }
    if (i < NN) rp[i] = tmp[threadIdx.x] - v;
    if (threadIdx.x == 255) bsum[blockIdx.x] = tmp[255];
}

__global__ void scan2_kernel(u32* bsum) {
    __shared__ u32 tmp[512];
    int tid = threadIdx.x;
    u32 v = (tid < 391) ? bsum[tid] : 0u;
    tmp[tid] = v;
    __syncthreads();
    for (int off = 1; off < 512; off <<= 1) {
        u32 t = (tid >= off) ? tmp[tid - off] : 0u;
        __syncthreads();
        tmp[tid] += t;
        __syncthreads();
    }
    if (tid < 391) bsum[tid] = tmp[tid] - v;
}

__global__ void scan3_kernel(u32* rp, const u32* __restrict__ bsum, u32* __restrict__ cursor) {
    int i = blockIdx.x * 256 + threadIdx.x;
    if (i < NN) {
        u32 v = rp[i] + bsum[blockIdx.x];
        rp[i] = v;
        cursor[i] = v;
    }
    if (blockIdx.x == 0 && threadIdx.x == 0) rp[NN] = EE;
}

__global__ void fill_kernel(const int* __restrict__ ei, u32* __restrict__ cursor,
                            int* __restrict__ csr) {
    int e = blockIdx.x * 256 + threadIdx.x;
    if (e < EE) {
        int s = ei[e], d = ei[EE + e];
        u32 p = atomicAdd(&cursor[d], 1u);
        csr[p] = s;
    }
}

// ---------------------------------------------------------------------------
// Gather: wave per node, lane = channel. Softmax without max-subtraction
// (|e| tiny here, exp safe); z factors out of the weighted sum.
// Fused bias+relu+linear+sigmoid epilogue; f32 output.
// ---------------------------------------------------------------------------
__global__ __launch_bounds__(256) void gather_kernel(
    const u32* __restrict__ xh,
    const float2* __restrict__ asrc,
    const float2* __restrict__ adst,
    const u32* __restrict__ rp,
    const int* __restrict__ csr,
    const float* __restrict__ gat_b,  // [64]
    const float* __restrict__ lin_w,  // [2*64]
    const float* __restrict__ lin_b,  // [2]
    float2* __restrict__ out)         // [NN] (y0,y1) f32
{
    int wv = threadIdx.x >> 6, lane = threadIdx.x & 63;
    int node = blockIdx.x * 4 + wv;
    float2 ad = adst[node];
    float2 as = asrc[node];
    // self-loop
    float e0 = as.x + ad.x; e0 = e0 > 0.f ? e0 : 0.2f * e0;
    float e1 = as.y + ad.y; e1 = e1 > 0.f ? e1 : 0.2f * e1;
    float w0 = exp2f(LOG2E * e0);
    float w1 = exp2f(LOG2E * e1);
    u32 u = xh[(size_t)node * 64 + lane];
    float acc0 = w0 * bflo(u), acc1 = w1 * bfhi(u);
    float z0 = w0, z1 = w1;
    u32 beg = rp[node], end = rp[node + 1];
    for (u32 p = beg; p < end; ++p) {
        int s = csr[p];
        float2 a2 = asrc[s];
        u32 uu = xh[(size_t)s * 64 + lane];
        float f0 = a2.x + ad.x; f0 = f0 > 0.f ? f0 : 0.2f * f0;
        float f1 = a2.y + ad.y; f1 = f1 > 0.f ? f1 : 0.2f * f1;
        float v0 = exp2f(LOG2E * f0);
        float v1 = exp2f(LOG2E * f1);
        acc0 = fmaf(v0, bflo(uu), acc0);
        acc1 = fmaf(v1, bfhi(uu), acc1);
        z0 += v0;
        z1 += v1;
    }
    float od = 0.5f * (acc0 * fast_rcp(z0) + acc1 * fast_rcp(z1)) + gat_b[lane];
    od = fmaxf(od, 0.f);
    float p0 = od * lin_w[lane];
    float p1 = od * lin_w[64 + lane];
#pragma unroll
    for (int off = 32; off > 0; off >>= 1) {
        p0 += __shfl_xor(p0, off);
        p1 += __shfl_xor(p1, off);
    }
    if (lane == 0) {
        float y0 = fast_rcp(1.f + exp2f(-LOG2E * (p0 + lin_b[0])));
        float y1 = fast_rcp(1.f + exp2f(-LOG2E * (p1 + lin_b[1])));
        out[node] = make_float2(y0, y1);
    }
}

extern "C" void kernel_launch(void* const* d_in, const int* in_sizes, int n_in,
                              void* d_out, int out_size, void* d_ws, size_t ws_size,
                              hipStream_t stream) {
    const float2* x2 = (const float2*)d_in[0];
    const int* ei = (const int*)d_in[1];
    const float* w_ih = (const float*)d_in[2];
    const float* w_hh = (const float*)d_in[3];
    const float* b_ih = (const float*)d_in[4];
    const float* b_hh = (const float*)d_in[5];
    const float* gat_w = (const float*)d_in[6];
    const float* att_src = (const float*)d_in[7];
    const float* att_dst = (const float*)d_in[8];
    const float* gat_b = (const float*)d_in[9];
    const float* lin_w = (const float*)d_in[10];
    const float* lin_b = (const float*)d_in[11];

    char* w = (char*)d_ws;
    u16* h = (u16*)(w);                           // 12,800,000 B
    u32* xh = (u32*)(w + 12800000);               // 25,600,000 B
    float2* asrc = (float2*)(w + 38400000);       //    800,000 B
    float2* adst = (float2*)(w + 39200000);       //    800,000 B
    u32* rp = (u32*)(w + 40000000);               //    400,128 B (deg -> row_ptr)
    u32* cursor = (u32*)(w + 40400128);           //    400,000 B
    u32* bsum = (u32*)(w + 40800128);             //      2,048 B
    int* csr = (int*)(w + 40802176);              //  4,000,000 B

    hipMemsetAsync(rp, 0, (NN + 1) * sizeof(u32), stream);
    lstm_kernel<<<1563, 256, 0, stream>>>(x2, w_ih, w_hh, b_ih, b_hh, h);
    xh_kernel<<<NN / 4, 256, 0, stream>>>(h, gat_w, att_src, att_dst, xh, asrc, adst);
    hist_kernel<<<(EE + 255) / 256, 256, 0, stream>>>(ei, rp);
    scan1_kernel<<<391, 256, 0, stream>>>(rp, bsum);
    scan2_kernel<<<1, 512, 0, stream>>>(bsum);
    scan3_kernel<<<391, 256, 0, stream>>>(rp, bsum, cursor);
    fill_kernel<<<(EE + 255) / 256, 256, 0, stream>>>(ei, cursor, csr);
    gather_kernel<<<NN / 4, 256, 0, stream>>>(xh, asrc, adst, rp, csr, gat_b, lin_w, lin_b,
                                              (float2*)d_out);
}

// Round 3
// 1901.632 us; speedup vs baseline: 2.3979x; 2.3979x over previous
//
#include <hip/hip_runtime.h>

#define NN 100000
#define TT 64
#define EE 1000000
#define LOG2E 1.44269504088896340736f

typedef __attribute__((ext_vector_type(8))) short bf16x8;
typedef __attribute__((ext_vector_type(4))) float f32x4;
typedef unsigned int u32;
typedef unsigned short u16;

__device__ __forceinline__ float bflo(u32 u) { return __builtin_bit_cast(float, u << 16); }
__device__ __forceinline__ float bfhi(u32 u) { return __builtin_bit_cast(float, u & 0xffff0000u); }
__device__ __forceinline__ u16 f2bf(float f) {
    u32 u = __builtin_bit_cast(u32, f);
    return (u16)((u + 0x7fffu + ((u >> 16) & 1u)) >> 16);
}
__device__ __forceinline__ float fast_rcp(float x) { return __builtin_amdgcn_rcpf(x); }
__device__ __forceinline__ float sigf(float v) { return fast_rcp(1.f + exp2f(-LOG2E * v)); }
__device__ __forceinline__ float tanhf_fast(float v) {
    return fmaf(2.f, fast_rcp(1.f + exp2f(-2.f * LOG2E * v)), -1.f);
}

// ---------------------------------------------------------------------------
// LSTM: 16 nodes/wave, MFMA 16x16x32 bf16, K extended to 96:
//   gates = [h(64) | x0,x1,1] . [w_hh | w_ih | (b_ih+b_hh)]^T
// x staged to LDS once (coalesced float4 -> packed bf16).  No per-step global
// loads, no big per-lane weight arrays (kills round-2's 8.5 GB spill/x traffic).
// C/D: col=lane&15 (gate), row=(lane>>4)*4+reg (node). A: m=lane&15, k=8*(lane>>4)+j.
// LDS total 60.9 KB -> 2 blocks/CU.
// ---------------------------------------------------------------------------
__global__ __launch_bounds__(256, 2) void lstm_kernel(
    const float* __restrict__ x,     // [NN*TT*2]
    const float* __restrict__ w_ih,  // [256*2]
    const float* __restrict__ w_hh,  // [256*64]
    const float* __restrict__ b_ih,  // [256]
    const float* __restrict__ b_hh,  // [256]
    u16* __restrict__ h_out)         // [NN*64] bf16 (internal format)
{
    __shared__ __align__(16) u16 wfrag[32 * 64 * 8];   // 32 KB  B-fragments k<64
    __shared__ __align__(8) uint2 wf2[16 * 16];        //  2 KB  rows 64..66 (w_ih|bias)
    __shared__ __align__(8) u32 x_lds[4][16 * 66];     // 16.5 KB packed bf16 x (pad 66)
    __shared__ __align__(16) u16 h_buf[4][16 * 72];    //  9 KB  per-wave h (pad 72)

    const int tid = threadIdx.x;
    const int wv = tid >> 6, lane = tid & 63;
    const int q = lane >> 4, cl = lane & 15;
    const int node_base = (blockIdx.x * 4 + wv) * 16;

    // stage B = w_hh^T fragments: frag f=(t,kh); value (lane,j) = w_hh[t*16+cl][kh*32+q*8+j]
    for (int f = wv; f < 32; f += 4) {
        int t = f >> 1, kh = f & 1;
        int n = t * 16 + cl;
        int k = kh * 32 + q * 8;
        const float4* s4 = (const float4*)(w_hh + n * 64 + k);
        float4 u0 = s4[0], u1 = s4[1];
        u16* d = wfrag + (f * 64 + lane) * 8;
        d[0] = f2bf(u0.x); d[1] = f2bf(u0.y); d[2] = f2bf(u0.z); d[3] = f2bf(u0.w);
        d[4] = f2bf(u1.x); d[5] = f2bf(u1.y); d[6] = f2bf(u1.z); d[7] = f2bf(u1.w);
    }
    // stage K-rows 64..66 for each gate column: (w_ih[g][0], w_ih[g][1], bias[g], 0)
    {
        int t = tid >> 4, c = tid & 15;
        int g = t * 16 + c;
        u32 lo = (u32)f2bf(w_ih[g * 2 + 0]) | ((u32)f2bf(w_ih[g * 2 + 1]) << 16);
        u32 hi = (u32)f2bf(b_ih[g] + b_hh[g]);
        wf2[t * 16 + c] = make_uint2(lo, hi);
    }
    // stage x: per-wave 16 nodes x 64 steps, coalesced float4 (=2 steps), pack to bf16
    {
        u32* xl = x_lds[wv];
#pragma unroll
        for (int it = 0; it < 8; ++it) {
            int nl = it * 2 + (lane >> 5);
            int s = (lane * 2) & 63;
            int nd = node_base + nl;
            nd = nd < NN ? nd : NN - 1;
            float4 v = *(const float4*)(x + ((size_t)nd * 64 + s) * 2);
            u32 p0 = (u32)f2bf(v.x) | ((u32)f2bf(v.y) << 16);
            u32 p1 = (u32)f2bf(v.z) | ((u32)f2bf(v.w) << 16);
            *((uint2*)(xl + nl * 66 + s)) = make_uint2(p0, p1);
        }
    }
    // zero h (step 0 then runs the uniform 3-MFMA path)
    {
        u32* hz = (u32*)h_buf[wv];
        for (int i = lane; i < 576; i += 64) hz[i] = 0u;
    }
    __syncthreads();

    u16* hb = h_buf[wv];
    u32* xl = x_lds[wv];
    const bool q0 = (q == 0);
    const f32x4 zero4 = {0.f, 0.f, 0.f, 0.f};

    float cst[16];
#pragma unroll
    for (int i = 0; i < 16; ++i) cst[i] = 0.f;

    for (int step = 0; step < TT; ++step) {
        union { bf16x8 v; u32 u[4]; } a0u, a1u, a2u;
        a0u.v = *(const bf16x8*)(hb + cl * 72 + q * 8);
        a1u.v = *(const bf16x8*)(hb + cl * 72 + 32 + q * 8);
        u32 xp = xl[cl * 66 + step];
        a2u.u[0] = q0 ? xp : 0u;
        a2u.u[1] = q0 ? 0x00003F80u : 0u;  // k=66 -> bf16(1.0), k=67 -> 0
        a2u.u[2] = 0u;
        a2u.u[3] = 0u;

        f32x4 acc[16];
#pragma unroll
        for (int t = 0; t < 16; ++t) {
            bf16x8 b0 = *(const bf16x8*)(wfrag + ((t * 2 + 0) * 64 + lane) * 8);
            bf16x8 b1 = *(const bf16x8*)(wfrag + ((t * 2 + 1) * 64 + lane) * 8);
            uint2 bp = wf2[t * 16 + cl];
            union { bf16x8 v; u32 u[4]; } b2u;
            b2u.u[0] = q0 ? bp.x : 0u;
            b2u.u[1] = q0 ? bp.y : 0u;
            b2u.u[2] = 0u;
            b2u.u[3] = 0u;
            f32x4 a = __builtin_amdgcn_mfma_f32_16x16x32_bf16(a0u.v, b0, zero4, 0, 0, 0);
            a = __builtin_amdgcn_mfma_f32_16x16x32_bf16(a1u.v, b1, a, 0, 0, 0);
            acc[t] = __builtin_amdgcn_mfma_f32_16x16x32_bf16(a2u.v, b2u.v, a, 0, 0, 0);
        }
        // elementwise: unit j = tt*16+cl, node = q*4+r (gate tiles i|f|g|o x4)
#pragma unroll
        for (int r = 0; r < 4; ++r) {
#pragma unroll
            for (int tt = 0; tt < 4; ++tt) {
                float ig = sigf(acc[tt][r]);
                float fg = sigf(acc[tt + 4][r]);
                float gg = tanhf_fast(acc[tt + 8][r]);
                float og = sigf(acc[tt + 12][r]);
                float cc = fmaf(fg, cst[r * 4 + tt], ig * gg);
                cst[r * 4 + tt] = cc;
                hb[(q * 4 + r) * 72 + tt * 16 + cl] = f2bf(og * tanhf_fast(cc));
            }
        }
    }
    // write h to global (coalesced u32 pairs)
#pragma unroll
    for (int i = 0; i < 8; ++i) {
        int id = i * 64 + lane;
        int row = id >> 5, col2 = (id & 31) * 2;
        int nd = node_base + row;
        if (nd < NN) {
            u32 u = *(const u32*)(hb + row * 72 + col2);
            *((u32*)(h_out + (size_t)nd * 64 + col2)) = u;
        }
    }
}

// ---------------------------------------------------------------------------
// xh = h @ gat_w.T packed per-channel as (head0,head1) bf16 pair; attention dots
// one wave per node; f32 accumulation before bf16 rounding.
// ---------------------------------------------------------------------------
__global__ __launch_bounds__(256) void xh_kernel(
    const u16* __restrict__ h,        // [NN*64] bf16 (internal)
    const float* __restrict__ gat_w,  // [128*64] f32
    const float* __restrict__ att_src,// [2*64] f32
    const float* __restrict__ att_dst,// [2*64] f32
    u32* __restrict__ xh,             // [NN*64] packed bf16 pairs
    float2* __restrict__ asrc,
    float2* __restrict__ adst)
{
    __shared__ float hsh[4][64];
    int wv = threadIdx.x >> 6, lane = threadIdx.x & 63;
    int node = blockIdx.x * 4 + wv;
    hsh[wv][lane] = bflo((u32)h[(size_t)node * 64 + lane]);
    __syncthreads();
    const float4* w0p = (const float4*)(gat_w + (size_t)lane * 64);
    const float4* w1p = (const float4*)(gat_w + (size_t)(64 + lane) * 64);
    float a0 = 0.f, a1 = 0.f;
#pragma unroll
    for (int k = 0; k < 64; k += 4) {
        float4 w0 = w0p[k >> 2], w1 = w1p[k >> 2];
        float h0 = hsh[wv][k], h1 = hsh[wv][k + 1];
        float h2 = hsh[wv][k + 2], h3 = hsh[wv][k + 3];
        a0 = fmaf(h0, w0.x, a0); a0 = fmaf(h1, w0.y, a0);
        a0 = fmaf(h2, w0.z, a0); a0 = fmaf(h3, w0.w, a0);
        a1 = fmaf(h0, w1.x, a1); a1 = fmaf(h1, w1.y, a1);
        a1 = fmaf(h2, w1.z, a1); a1 = fmaf(h3, w1.w, a1);
    }
    xh[(size_t)node * 64 + lane] = (u32)f2bf(a0) | ((u32)f2bf(a1) << 16);
    float ps0 = a0 * att_src[lane];
    float ps1 = a1 * att_src[64 + lane];
    float pd0 = a0 * att_dst[lane];
    float pd1 = a1 * att_dst[64 + lane];
#pragma unroll
    for (int off = 32; off > 0; off >>= 1) {
        ps0 += __shfl_xor(ps0, off);
        ps1 += __shfl_xor(ps1, off);
        pd0 += __shfl_xor(pd0, off);
        pd1 += __shfl_xor(pd1, off);
    }
    if (lane == 0) {
        asrc[node] = make_float2(ps0, ps1);
        adst[node] = make_float2(pd0, pd1);
    }
}

// ------------------------- CSR build -------------------------
__global__ void hist_kernel(const int* __restrict__ ei, u32* __restrict__ deg) {
    int e = blockIdx.x * 256 + threadIdx.x;
    if (e < EE) atomicAdd(&deg[ei[EE + e]], 1u);
}

__global__ void scan1_kernel(u32* rp, u32* bsum) {
    __shared__ u32 tmp[256];
    int i = blockIdx.x * 256 + threadIdx.x;
    u32 v = (i < NN) ? rp[i] : 0u;
    tmp[threadIdx.x] = v;
    __syncthreads();
    for (int off = 1; off < 256; off <<= 1) {
        u32 t = (threadIdx.x >= (u32)off) ? tmp[threadIdx.x - off] : 0u;
        __syncthreads();
        tmp[threadIdx.x] += t;
        __syncthreads();
    }
    if (i < NN) rp[i] = tmp[threadIdx.x] - v;
    if (threadIdx.x == 255) bsum[blockIdx.x] = tmp[255];
}

__global__ void scan2_kernel(u32* bsum) {
    __shared__ u32 tmp[512];
    int tid = threadIdx.x;
    u32 v = (tid < 391) ? bsum[tid] : 0u;
    tmp[tid] = v;
    __syncthreads();
    for (int off = 1; off < 512; off <<= 1) {
        u32 t = (tid >= off) ? tmp[tid - off] : 0u;
        __syncthreads();
        tmp[tid] += t;
        __syncthreads();
    }
    if (tid < 391) bsum[tid] = tmp[tid] - v;
}

__global__ void scan3_kernel(u32* rp, const u32* __restrict__ bsum, u32* __restrict__ cursor) {
    int i = blockIdx.x * 256 + threadIdx.x;
    if (i < NN) {
        u32 v = rp[i] + bsum[blockIdx.x];
        rp[i] = v;
        cursor[i] = v;
    }
    if (blockIdx.x == 0 && threadIdx.x == 0) rp[NN] = EE;
}

__global__ void fill_kernel(const int* __restrict__ ei, u32* __restrict__ cursor,
                            int* __restrict__ csr) {
    int e = blockIdx.x * 256 + threadIdx.x;
    if (e < EE) {
        int s = ei[e], d = ei[EE + e];
        u32 p = atomicAdd(&cursor[d], 1u);
        csr[p] = s;
    }
}

// ---------------------------------------------------------------------------
// Gather: wave per node, lane = channel. Softmax without max-subtraction
// (|e| tiny, exp safe); z factors out of the weighted sum.
// Fused bias+relu+linear+sigmoid epilogue; f32 output.
// ---------------------------------------------------------------------------
__global__ __launch_bounds__(256) void gather_kernel(
    const u32* __restrict__ xh,
    const float2* __restrict__ asrc,
    const float2* __restrict__ adst,
    const u32* __restrict__ rp,
    const int* __restrict__ csr,
    const float* __restrict__ gat_b,  // [64]
    const float* __restrict__ lin_w,  // [2*64]
    const float* __restrict__ lin_b,  // [2]
    float2* __restrict__ out)         // [NN] (y0,y1) f32
{
    int wv = threadIdx.x >> 6, lane = threadIdx.x & 63;
    int node = blockIdx.x * 4 + wv;
    float2 ad = adst[node];
    float2 as = asrc[node];
    // self-loop
    float e0 = as.x + ad.x; e0 = e0 > 0.f ? e0 : 0.2f * e0;
    float e1 = as.y + ad.y; e1 = e1 > 0.f ? e1 : 0.2f * e1;
    float w0 = exp2f(LOG2E * e0);
    float w1 = exp2f(LOG2E * e1);
    u32 u = xh[(size_t)node * 64 + lane];
    float acc0 = w0 * bflo(u), acc1 = w1 * bfhi(u);
    float z0 = w0, z1 = w1;
    u32 beg = rp[node], end = rp[node + 1];
    for (u32 p = beg; p < end; ++p) {
        int s = csr[p];
        float2 a2 = asrc[s];
        u32 uu = xh[(size_t)s * 64 + lane];
        float f0 = a2.x + ad.x; f0 = f0 > 0.f ? f0 : 0.2f * f0;
        float f1 = a2.y + ad.y; f1 = f1 > 0.f ? f1 : 0.2f * f1;
        float v0 = exp2f(LOG2E * f0);
        float v1 = exp2f(LOG2E * f1);
        acc0 = fmaf(v0, bflo(uu), acc0);
        acc1 = fmaf(v1, bfhi(uu), acc1);
        z0 += v0;
        z1 += v1;
    }
    float od = 0.5f * (acc0 * fast_rcp(z0) + acc1 * fast_rcp(z1)) + gat_b[lane];
    od = fmaxf(od, 0.f);
    float p0 = od * lin_w[lane];
    float p1 = od * lin_w[64 + lane];
#pragma unroll
    for (int off = 32; off > 0; off >>= 1) {
        p0 += __shfl_xor(p0, off);
        p1 += __shfl_xor(p1, off);
    }
    if (lane == 0) {
        float y0 = fast_rcp(1.f + exp2f(-LOG2E * (p0 + lin_b[0])));
        float y1 = fast_rcp(1.f + exp2f(-LOG2E * (p1 + lin_b[1])));
        out[node] = make_float2(y0, y1);
    }
}

extern "C" void kernel_launch(void* const* d_in, const int* in_sizes, int n_in,
                              void* d_out, int out_size, void* d_ws, size_t ws_size,
                              hipStream_t stream) {
    const float* x = (const float*)d_in[0];
    const int* ei = (const int*)d_in[1];
    const float* w_ih = (const float*)d_in[2];
    const float* w_hh = (const float*)d_in[3];
    const float* b_ih = (const float*)d_in[4];
    const float* b_hh = (const float*)d_in[5];
    const float* gat_w = (const float*)d_in[6];
    const float* att_src = (const float*)d_in[7];
    const float* att_dst = (const float*)d_in[8];
    const float* gat_b = (const float*)d_in[9];
    const float* lin_w = (const float*)d_in[10];
    const float* lin_b = (const float*)d_in[11];

    char* w = (char*)d_ws;
    u16* h = (u16*)(w);                           // 12,800,000 B
    u32* xh = (u32*)(w + 12800000);               // 25,600,000 B
    float2* asrc = (float2*)(w + 38400000);       //    800,000 B
    float2* adst = (float2*)(w + 39200000);       //    800,000 B
    u32* rp = (u32*)(w + 40000000);               //    400,128 B (deg -> row_ptr)
    u32* cursor = (u32*)(w + 40400128);           //    400,000 B
    u32* bsum = (u32*)(w + 40800128);             //      2,048 B
    int* csr = (int*)(w + 40802176);              //  4,000,000 B

    hipMemsetAsync(rp, 0, (NN + 1) * sizeof(u32), stream);
    lstm_kernel<<<1563, 256, 0, stream>>>(x, w_ih, w_hh, b_ih, b_hh, h);
    xh_kernel<<<NN / 4, 256, 0, stream>>>(h, gat_w, att_src, att_dst, xh, asrc, adst);
    hist_kernel<<<(EE + 255) / 256, 256, 0, stream>>>(ei, rp);
    scan1_kernel<<<391, 256, 0, stream>>>(rp, bsum);
    scan2_kernel<<<1, 512, 0, stream>>>(bsum);
    scan3_kernel<<<391, 256, 0, stream>>>(rp, bsum, cursor);
    fill_kernel<<<(EE + 255) / 256, 256, 0, stream>>>(ei, cursor, csr);
    gather_kernel<<<NN / 4, 256, 0, stream>>>(xh, asrc, adst, rp, csr, gat_b, lin_w, lin_b,
                                              (float2*)d_out);
}